// Round 18
// baseline (324.168 us; speedup 1.0000x reference)
//
#include <hip/hip_runtime.h>

typedef __attribute__((ext_vector_type(4)))  float f32x4;
typedef __attribute__((ext_vector_type(16))) float f32x16;
typedef __attribute__((ext_vector_type(8)))  short bf16x8;
typedef __attribute__((ext_vector_type(4)))  short short4v;

#define NEDGE 100000
#define NNODE 10000
#define INV40f 0.15811388300841897f
#define INV120f 0.09128709291752769f

__device__ inline short f2bf(float f) {
    unsigned u = __builtin_bit_cast(unsigned, f);
    u = (u + 0x7fffu + ((u >> 16) & 1u)) >> 16;
    return (short)u;
}

__device__ __forceinline__ float bperm(int byteIdx, float v) {
    return __builtin_bit_cast(float,
        __builtin_amdgcn_ds_bpermute(byteIdx, __builtin_bit_cast(int, v)));
}

__device__ __forceinline__ void stage16(const void* gsrc, void* ldst) {
    __builtin_amdgcn_global_load_lds(
        (const __attribute__((address_space(1))) unsigned*)gsrc,
        (__attribute__((address_space(3))) unsigned*)(unsigned long long)(uintptr_t)ldst,
        16, 0, 0);
}

#define MFMA32(A,B,C) __builtin_amdgcn_mfma_f32_32x32x16_bf16((A),(B),(C),0,0,0)

// prep: fc2_w [64k][1600c] -> fc2_wt FRAGMENT-MAJOR (R14); fc1_w -> fc1_wt; zero stats+hist+flags
__global__ __launch_bounds__(256) void prep(const float* __restrict__ fc1_w,
                                            const float* __restrict__ fc2_w,
                                            short* __restrict__ fc1_wt,
                                            short* __restrict__ fc2_wt,
                                            float* __restrict__ stats,
                                            int* __restrict__ hist,
                                            int* __restrict__ flags) {
    const int b = blockIdx.x, t = threadIdx.x;
    if (b < 25) {
        __shared__ short tile[64 * 66];
        const int c0 = b * 64;
        #pragma unroll
        for (int rep = 0; rep < 16; rep++) {
            const int idx = rep * 256 + t;
            const int k = idx >> 6, c = idx & 63;
            tile[k * 66 + c] = f2bf(fc2_w[(size_t)k * 1600 + c0 + c]);
        }
        __syncthreads();
        short* outp = fc2_wt + b * 4096;
        #pragma unroll
        for (int rep = 0; rep < 16; rep++) {
            const int og = rep * 256 + t;      // 0..4095
            const int g2rel = og >> 11;
            const int t2 = (og >> 8) & 7;
            const int cl = ((og >> 3) & 31) + g2rel * 32;
            const int j = og & 7;
            const int k = (t2 >> 1) * 16 + (t2 & 1) * 8 + j;
            outp[og] = tile[k * 66 + cl];
        }
    } else if (b == 25) {
        #pragma unroll
        for (int rep = 0; rep < 16; rep++) {
            const int i = rep * 256 + t;
            fc1_wt[(i & 63) * 64 + (i >> 6)] = f2bf(fc1_w[i]);
        }
    } else if (b == 26) {
        if (t < 72) stats[t] = 0.0f;
        if (t >= 72 && t < 74) flags[t - 72] = 0;
    } else {
        const int i = (b - 27) * 256 + t;
        if (i < NNODE) hist[i] = 0;
    }
}

// R14-exact: 4 waves/block, 32 edges/wave via 32x32x16 MFMA; fc2_wt staged via LINEAR DMA
// (13 x 16KB chunks, dbuf); fragment-major layout -> conflict-free ds_reads, no swizzle.
__global__ __launch_bounds__(256, 2) void edge_fused(
    const float* __restrict__ node_attr,
    const float* __restrict__ edge_attr,
    const float* __restrict__ edge_sh,
    const int*   __restrict__ edge_index,
    const float* __restrict__ fc1_b,
    const float* __restrict__ fc2_b,
    const short* __restrict__ fc1_wt,
    const short* __restrict__ fc2_wt,
    float* __restrict__ tp_out,
    int*   __restrict__ hist)
{
    // LDS: cbA 16384 @0 | cbB 16384 @16384 (h_s alias) | shb 4x512 @32768 | bias 6400 @34816
    __shared__ __align__(16) char lds[41216];
    char* cbA = lds;
    char* cbB = lds + 16384;
    float* bias_s = (float*)(lds + 34816);

    const int tid  = threadIdx.x;
    const int wid  = tid >> 6;          // 0..3
    const int wtid = tid & 63;
    const int l31  = wtid & 31;
    const int half = wtid >> 5;
    const int e0   = blockIdx.x * 128 + wid * 32;
    const bool active = (e0 < NEDGE);   // NEDGE % 32 == 0: whole waves

    char*  h_s = cbB + wid * 4096;      // [32 edges][128B] bf16, swizzled; dead before phase-1 DMA
    float* shb = (float*)(lds + 32768 + wid * 512);
    const int swzl = (l31 & 7) << 4;

#define STAGE1(CH, BUF, J) do { \
        const int _o = (wid * 4 + (J)) * 1024 + wtid * 16; \
        stage16((const char*)fc2_wt + (CH) * 16384 + _o, (BUF) + (wid * 4 + (J)) * 1024); \
    } while (0)
#define STAGE_FULL(CH, BUF) do { STAGE1(CH,BUF,0); STAGE1(CH,BUF,1); STAGE1(CH,BUF,2); STAGE1(CH,BUF,3); } while (0)

    STAGE_FULL(0, cbA);   // chunk 0 in flight; overlaps prologue (cbA untouched below)

    // ---- bias -> LDS (400 f32x4) ----
    *(f32x4*)(bias_s + tid * 4) = *(const f32x4*)(fc2_b + tid * 4);
    if (tid < 144)
        *(f32x4*)(bias_s + (tid + 256) * 4) = *(const f32x4*)(fc2_b + (tid + 256) * 4);

    // ---- edge meta: lanes 0..31 own one edge ----
    int dst_r = 0;
    if (active && wtid < 32) {
        dst_r = edge_index[NEDGE + e0 + wtid];
        atomicAdd(&hist[edge_index[e0 + wtid]], 1);
        *(f32x4*)(shb + wtid * 4) = *(const f32x4*)(edge_sh + (size_t)(e0 + wtid) * 4);
    }

    bf16x8 hb[4];
    f32x4 shv = {0.f, 0.f, 0.f, 0.f};
    float cb1r[16], c10r[12], c11r[4];
    int vs[2];
    vs[0] = l31 * 4;
    vs[1] = (32 + l31) * 4;

    if (active) {
        const int dstm = __shfl(dst_r, l31, 64);
        const float* nap = node_attr + (size_t)dstm * 56;
        shv = *(const f32x4*)(shb + l31 * 4);   // same-wave LDS RAW, in-order

        const f32x4 t0 = *(const f32x4*)(nap + half * 16);
        const f32x4 t1 = *(const f32x4*)(nap + half * 16 + 4);
        const f32x4 t2 = *(const f32x4*)(nap + half * 16 + 8);
        const f32x4 t3 = *(const f32x4*)(nap + half * 16 + 12);
        #pragma unroll
        for (int j = 0; j < 4; j++) {
            cb1r[j]      = INV40f * t0[j];
            cb1r[4 + j]  = INV40f * t1[j];
            cb1r[8 + j]  = INV40f * t2[j];
            cb1r[12 + j] = INV40f * t3[j];
        }
        const f32x4 y0 = *(const f32x4*)(nap + 32 + half * 12);
        const f32x4 y1 = *(const f32x4*)(nap + 32 + half * 12 + 4);
        const f32x4 y2 = *(const f32x4*)(nap + 32 + half * 12 + 8);
        float xx[12];
        #pragma unroll
        for (int j = 0; j < 4; j++) { xx[j] = y0[j]; xx[4 + j] = y1[j]; xx[8 + j] = y2[j]; }
        const float i40s0 = INV40f * shv[0];
        #pragma unroll
        for (int k = 0; k < 12; k++) c10r[k] = i40s0 * xx[k];
        #pragma unroll
        for (int e = 0; e < 4; e++)
            c11r[e] = INV120f * (xx[e*3]*shv[1] + xx[e*3+1]*shv[2] + xx[e*3+2]*shv[3]);

        // ---- fc1: h = relu(ea @ fc1_w + b) with 32x32x16 MFMA ----
        const float* pe = edge_attr + (size_t)(e0 + l31) * 64 + half * 8;
        bf16x8 eb[4];
        #pragma unroll
        for (int s = 0; s < 4; s++) {
            const f32x4 a = *(const f32x4*)(pe + s * 16);
            const f32x4 b = *(const f32x4*)(pe + s * 16 + 4);
            #pragma unroll
            for (int i = 0; i < 4; i++) { eb[s][i] = f2bf(a[i]); eb[s][4 + i] = f2bf(b[i]); }
        }
        #pragma unroll
        for (int g = 0; g < 2; g++) {
            f32x16 c;
            #pragma unroll
            for (int q = 0; q < 4; q++) {
                const f32x4 bq = *(const f32x4*)(fc1_b + g*32 + q*8 + half*4);
                c[q*4+0] = bq[0]; c[q*4+1] = bq[1]; c[q*4+2] = bq[2]; c[q*4+3] = bq[3];
            }
            #pragma unroll
            for (int s = 0; s < 4; s++) {
                const bf16x8 af = *(const bf16x8*)(fc1_wt + (g*32 + l31)*64 + s*16 + half*8);
                c = MFMA32(af, eb[s], c);
            }
            #pragma unroll
            for (int q = 0; q < 4; q++) {
                short4v p;
                #pragma unroll
                for (int j = 0; j < 4; j++) p[j] = f2bf(fmaxf(c[q*4+j], 0.0f));
                *(short4v*)(h_s + (l31*128 + ((g*64 + q*16 + half*8) ^ swzl))) = p;
            }
        }
        #pragma unroll
        for (int s = 0; s < 4; s++)
            hb[s] = *(const bf16x8*)(h_s + (l31*128 + ((s*32 + half*16) ^ swzl)));
    }

    // ---- fc2 + TP consume ----
    float acc0[16] = {};
    float ab1[4] = {0,0,0,0};
    float b2[12] = {};

    auto mload = [&](const char* cb, int go, int G) -> f32x16 {
        f32x16 c;
        #pragma unroll
        for (int q = 0; q < 4; q++) {
            const f32x4 bq = *(const f32x4*)(bias_s + G*32 + q*8 + half*4);
            c[q*4+0] = bq[0]; c[q*4+1] = bq[1]; c[q*4+2] = bq[2]; c[q*4+3] = bq[3];
        }
        #pragma unroll
        for (int s = 0; s < 4; s++) {
            const bf16x8 a = *(const bf16x8*)(cb + go*4096 + (s*2 + half)*512 + l31*16);
            c = MFMA32(a, hb[s], c);
        }
        return c;
    };

    auto cons_w00 = [&](const char* cb, int ch) {
        #pragma unroll
        for (int go = 0; go < 4; go++) {
            const int G = ch * 4 + go;                  // u = G
            const f32x16 c = mload(cb, go, G);
            const float cv = shv[0] * bperm(vs[G >> 4], cb1r[G & 15]);
            #pragma unroll
            for (int r = 0; r < 16; r++) acc0[r] += cv * c[r];
        }
    };
    auto cons_w01 = [&](const char* cb, int Gl0) {
        #pragma unroll
        for (int go = 0; go < 4; go++) {
            const int Gl = Gl0 + go;                    // 0..7
            const f32x16 c = mload(cb, go, 32 + Gl);
            #pragma unroll
            for (int q = 0; q < 4; q++) {
                const int u = Gl * 4 + q;               // 0..31
                const float cvq = bperm(vs[u >> 4], cb1r[u & 15]);
                #pragma unroll
                for (int j = 0; j < 4; j++) ab1[j] += cvq * c[q*4+j];
            }
        }
    };
    auto cons_w10 = [&](const char* cb) {
        #pragma unroll
        for (int go = 0; go < 2; go++) {
            const f32x16 c = mload(cb, go, 40 + go);
            #pragma unroll
            for (int q = 0; q < 4; q++) {
                const int u = go * 4 + q;               // 0..7
                #pragma unroll
                for (int i = 0; i < 3; i++) {
                    const float cv = bperm(vs[u >> 2], c10r[(u & 3) * 3 + i]);
                    #pragma unroll
                    for (int j = 0; j < 4; j++) b2[j*3+i] += cv * c[q*4+j];
                }
            }
        }
    };
    auto cons_w11_2 = [&](const char* cb, int goBase, int Gl0) {
        #pragma unroll
        for (int go = 0; go < 2; go++) {
            const int Gl = Gl0 + go;                    // u = Gl (0..7)
            const f32x16 c = mload(cb, goBase + go, 42 + Gl);
            const float cv = bperm(vs[Gl >> 2], c11r[Gl & 3]);
            #pragma unroll
            for (int r = 0; r < 16; r++) acc0[r] += cv * c[r];
        }
    };
    auto cons_w11_4 = [&](const char* cb, int Gl0) {
        #pragma unroll
        for (int go = 0; go < 4; go++) {
            const int Gl = Gl0 + go;
            const f32x16 c = mload(cb, go, 42 + Gl);
            const float cv = bperm(vs[Gl >> 2], c11r[Gl & 3]);
            #pragma unroll
            for (int r = 0; r < 16; r++) acc0[r] += cv * c[r];
        }
    };

    // ---- 13-phase chunk pipeline ----
    __syncthreads();                                   // chunk 0 + bias ready; h reads done
    STAGE_FULL(1,  cbB); if (active) cons_w00(cbA, 0); __syncthreads();
    STAGE_FULL(2,  cbA); if (active) cons_w00(cbB, 1); __syncthreads();
    STAGE_FULL(3,  cbB); if (active) cons_w00(cbA, 2); __syncthreads();
    STAGE_FULL(4,  cbA); if (active) cons_w00(cbB, 3); __syncthreads();
    STAGE_FULL(5,  cbB); if (active) cons_w00(cbA, 4); __syncthreads();
    STAGE_FULL(6,  cbA); if (active) cons_w00(cbB, 5); __syncthreads();
    STAGE_FULL(7,  cbB); if (active) cons_w00(cbA, 6); __syncthreads();
    STAGE_FULL(8,  cbA); if (active) cons_w00(cbB, 7); __syncthreads();
    STAGE_FULL(9,  cbB); if (active) cons_w01(cbA, 0); __syncthreads();
    STAGE_FULL(10, cbA); if (active) cons_w01(cbB, 4); __syncthreads();
    STAGE_FULL(11, cbB); if (active) { cons_w10(cbA); cons_w11_2(cbA, 2, 0); } __syncthreads();
    STAGE_FULL(12, cbA); if (active) cons_w11_4(cbB, 2); __syncthreads();
                         if (active) cons_w11_2(cbA, 0, 6);

    if (!active) return;

    // ---- emit ----
    float* orow = tp_out + (size_t)(e0 + l31) * 56;
    #pragma unroll
    for (int q = 0; q < 4; q++)
        *(f32x4*)(orow + q*8 + half*4) = f32x4{acc0[q*4], acc0[q*4+1], acc0[q*4+2], acc0[q*4+3]};
    float ov[12];
    #pragma unroll
    for (int j = 0; j < 4; j++) {
        ov[j*3 + 0] = shv[1] * ab1[j] + b2[j*3 + 0];
        ov[j*3 + 1] = shv[2] * ab1[j] + b2[j*3 + 1];
        ov[j*3 + 2] = shv[3] * ab1[j] + b2[j*3 + 2];
    }
    float* p1 = orow + 32 + half * 12;
    *(f32x4*)(p1)     = f32x4{ov[0], ov[1], ov[2],  ov[3]};
    *(f32x4*)(p1 + 4) = f32x4{ov[4], ov[5], ov[6],  ov[7]};
    *(f32x4*)(p1 + 8) = f32x4{ov[8], ov[9], ov[10], ov[11]};
#undef STAGE1
#undef STAGE_FULL
}

// fused scan + fill_perm. 391 blocks x 256 (all co-resident: tiny LDS/VGPR).
// Block 0 scans hist -> offsets/cursor, release-stores flag; others acquire-spin.
__global__ __launch_bounds__(256) void scanfill(const int* __restrict__ hist,
                                                const int* __restrict__ edge_index,
                                                int* __restrict__ offsets,
                                                int* __restrict__ cursor,
                                                int* __restrict__ perm,
                                                int* __restrict__ flag) {
    const int t = threadIdx.x;
    if (blockIdx.x == 0) {
        __shared__ int wsum[4];
        const int lane = t & 63;
        const int w = t >> 6;
        const int n0 = t * 40;
        int s = 0;
        if (n0 < NNODE) {
            for (int j = 0; j < 40; j++) s += hist[n0 + j];
        }
        int incl = s;
        #pragma unroll
        for (int d = 1; d < 64; d <<= 1) {
            const int v = __shfl_up(incl, d, 64);
            if (lane >= d) incl += v;
        }
        if (lane == 63) wsum[w] = incl;
        __syncthreads();
        int base = 0;
        for (int ww = 0; ww < 4; ww++) base += (ww < w) ? wsum[ww] : 0;
        if (n0 < NNODE) {
            int run = base + incl - s;
            for (int j = 0; j < 40; j++) {
                const int h = hist[n0 + j];
                offsets[n0 + j] = run; cursor[n0 + j] = run; run += h;
            }
        }
        if (t == 0) offsets[NNODE] = NEDGE;
        __syncthreads();
        if (t == 0) {
            __threadfence();
            __hip_atomic_store(flag, 1, __ATOMIC_RELEASE, __HIP_MEMORY_SCOPE_AGENT);
        }
        __syncthreads();
    } else {
        if (t == 0) {
            while (__hip_atomic_load(flag, __ATOMIC_ACQUIRE, __HIP_MEMORY_SCOPE_AGENT) == 0)
                __builtin_amdgcn_s_sleep(2);
        }
        __syncthreads();
        __threadfence();
    }
    const int e = blockIdx.x * 256 + t;
    if (e < NEDGE) {
        const int s = edge_index[e];
        const int p = atomicAdd(&cursor[s], 1);
        perm[p] = e;
    }
}

// fused node_agg + node_norm: 625 blocks x 256 (all co-resident). Aggregate -> stats
// atomics -> done-counter -> spin to 625 -> normalize register-held vals -> single store.
__global__ __launch_bounds__(256) void node_aggnorm(
    const float* __restrict__ tp_out, const int* __restrict__ offsets,
    const int* __restrict__ perm,
    const float* __restrict__ node_attr, float* __restrict__ out,
    float* __restrict__ stats, int* __restrict__ done,
    const float* __restrict__ g0, const float* __restrict__ b0,
    const float* __restrict__ g1)
{
    __shared__ float part[72];
    const int tid = threadIdx.x;
    if (tid < 72) part[tid] = 0.0f;
    __syncthreads();
    const int n = blockIdx.x * 16 + (tid >> 4);   // 625*16 = 10000 exact
    const int q = tid & 15;
    const bool act = (q < 14);
    f32x4 val = {0.f, 0.f, 0.f, 0.f};
    const int c0 = q * 4;
    if (act) {
        const int st = offsets[n], en = offsets[n + 1];
        f32x4 acc = {0.f, 0.f, 0.f, 0.f};
        for (int r = st; r < en; r++)
            acc += *(const f32x4*)(tp_out + (size_t)perm[r] * 56 + c0);
        const float inv = 1.0f / fmaxf((float)(en - st), 1.0f);
        const f32x4 res = *(const f32x4*)(node_attr + (size_t)n * 56 + c0);
        #pragma unroll
        for (int j = 0; j < 4; j++) {
            val[j] = acc[j] * inv + res[j];
            const int c = c0 + j;
            if (c < 32) {
                atomicAdd(&part[c], val[j]);
                atomicAdd(&part[32 + c], val[j] * val[j]);
            } else {
                atomicAdd(&part[64 + (c - 32) / 3], val[j] * val[j]);
            }
        }
    }
    __syncthreads();
    if (tid < 72) unsafeAtomicAdd(&stats[tid], part[tid]);
    __syncthreads();
    if (tid == 0) {
        __threadfence();
        atomicAdd(done, 1);
        while (__hip_atomic_load(done, __ATOMIC_ACQUIRE, __HIP_MEMORY_SCOPE_AGENT) < 625)
            __builtin_amdgcn_s_sleep(2);
    }
    __syncthreads();
    __threadfence();
    if (act) {
        #pragma unroll
        for (int j = 0; j < 4; j++) {
            const int c = c0 + j;
            if (c < 32) {
                const float m   = stats[c]      * (1.0f / NNODE);
                const float ex2 = stats[32 + c] * (1.0f / NNODE);
                const float var = ex2 - m * m;
                val[j] = (val[j] - m) * rsqrtf(var + 1e-5f) * g0[c] + b0[c];
            } else {
                const int v = (c - 32) / 3;
                const float vn = stats[64 + v] * (1.0f / (3.0f * NNODE));
                val[j] = val[j] * rsqrtf(vn + 1e-5f) * g1[v];
            }
        }
        *(f32x4*)(out + (size_t)n * 56 + c0) = val;
    }
}

extern "C" void kernel_launch(void* const* d_in, const int* in_sizes, int n_in,
                              void* d_out, int out_size, void* d_ws, size_t ws_size,
                              hipStream_t stream) {
    const float* node_attr = (const float*)d_in[0];
    const float* edge_attr = (const float*)d_in[1];
    const float* edge_sh   = (const float*)d_in[2];
    const int*   edge_index= (const int*)  d_in[3];
    const float* fc1_w     = (const float*)d_in[4];
    const float* fc1_b     = (const float*)d_in[5];
    const float* fc2_w     = (const float*)d_in[6];
    const float* fc2_b     = (const float*)d_in[7];
    const float* g0        = (const float*)d_in[8];
    const float* b0        = (const float*)d_in[9];
    const float* g1        = (const float*)d_in[10];
    float* out = (float*)d_out;

    char* ws = (char*)d_ws;
    // stats@0 288 | hist@288 40000 | offsets@40288 40004 (end 80292) | flags@80296 8 |
    // cursor@80320 40000 | perm@120320 400000 | fc1_wt@520320 | fc2_wt@528512 | tp_out@733312
    float* stats   = (float*)(ws + 0);
    int*   hist    = (int*)  (ws + 288);
    int*   offsets = (int*)  (ws + 40288);
    int*   flags   = (int*)  (ws + 80296);   // [0]=scan flag, [1]=agg done
    int*   cursor  = (int*)  (ws + 80320);
    int*   perm    = (int*)  (ws + 120320);
    short* fc1_wt  = (short*)(ws + 520320);
    short* fc2_wt  = (short*)(ws + 528512);
    float* tp_out  = (float*)(ws + 733312);

    prep<<<67, 256, 0, stream>>>(fc1_w, fc2_w, fc1_wt, fc2_wt, stats, hist, flags);
    edge_fused<<<782, 256, 0, stream>>>(node_attr, edge_attr, edge_sh, edge_index,
                                        fc1_b, fc2_b, fc1_wt, fc2_wt, tp_out, hist);
    scanfill<<<391, 256, 0, stream>>>(hist, edge_index, offsets, cursor, perm, flags);
    node_aggnorm<<<625, 256, 0, stream>>>(tp_out, offsets, perm, node_attr, out,
                                          stats, flags + 1, g0, b0, g1);
}

// Round 19
// 100.791 us; speedup vs baseline: 3.2163x; 3.2163x over previous
//
#include <hip/hip_runtime.h>

typedef __attribute__((ext_vector_type(4)))  float f32x4;
typedef __attribute__((ext_vector_type(16))) float f32x16;
typedef __attribute__((ext_vector_type(8)))  short bf16x8;
typedef __attribute__((ext_vector_type(4)))  short short4v;

#define NEDGE 100000
#define NNODE 10000
#define INV40f 0.15811388300841897f
#define INV120f 0.09128709291752769f

__device__ inline short f2bf(float f) {
    unsigned u = __builtin_bit_cast(unsigned, f);
    u = (u + 0x7fffu + ((u >> 16) & 1u)) >> 16;
    return (short)u;
}

__device__ __forceinline__ float bperm(int byteIdx, float v) {
    return __builtin_bit_cast(float,
        __builtin_amdgcn_ds_bpermute(byteIdx, __builtin_bit_cast(int, v)));
}

__device__ __forceinline__ void stage16(const void* gsrc, void* ldst) {
    __builtin_amdgcn_global_load_lds(
        (const __attribute__((address_space(1))) unsigned*)gsrc,
        (__attribute__((address_space(3))) unsigned*)(unsigned long long)(uintptr_t)ldst,
        16, 0, 0);
}

#define MFMA32(A,B,C) __builtin_amdgcn_mfma_f32_32x32x16_bf16((A),(B),(C),0,0,0)

// prep: fc2_w [64k][1600c] -> fc2_wt in FRAGMENT-MAJOR layout:
//   short index = chunk*8192 + g2*2048 + t*256 + c*8 + j ; k = (t>>1)*16 + (t&1)*8 + j
// so edge_fused stages with PURE LINEAR global reads and reads LDS conflict-free without swizzle.
__global__ __launch_bounds__(256) void prep(const float* __restrict__ fc1_w,
                                            const float* __restrict__ fc2_w,
                                            short* __restrict__ fc1_wt,
                                            short* __restrict__ fc2_wt,
                                            float* __restrict__ stats,
                                            int* __restrict__ hist) {
    const int b = blockIdx.x, t = threadIdx.x;
    if (b < 25) {
        __shared__ short tile[64 * 66];
        const int c0 = b * 64;
        #pragma unroll
        for (int rep = 0; rep < 16; rep++) {
            const int idx = rep * 256 + t;
            const int k = idx >> 6, c = idx & 63;
            tile[k * 66 + c] = f2bf(fc2_w[(size_t)k * 1600 + c0 + c]);
        }
        __syncthreads();
        short* outp = fc2_wt + b * 4096;
        #pragma unroll
        for (int rep = 0; rep < 16; rep++) {
            const int og = rep * 256 + t;      // 0..4095
            const int g2rel = og >> 11;
            const int t2 = (og >> 8) & 7;
            const int cl = ((og >> 3) & 31) + g2rel * 32;
            const int j = og & 7;
            const int k = (t2 >> 1) * 16 + (t2 & 1) * 8 + j;
            outp[og] = tile[k * 66 + cl];
        }
    } else if (b == 25) {
        #pragma unroll
        for (int rep = 0; rep < 16; rep++) {
            const int i = rep * 256 + t;
            fc1_wt[(i & 63) * 64 + (i >> 6)] = f2bf(fc1_w[i]);
        }
    } else if (b == 26) {
        if (t < 72) stats[t] = 0.0f;
    } else {
        const int i = (b - 27) * 256 + t;
        if (i < NNODE) hist[i] = 0;
    }
}

// 4 waves/block, 32 edges/wave via 32x32x16 MFMA. fc2_wt staged via LINEAR DMA
// (13 x 16KB chunks, dbuf); fragment-major layout makes ds_reads conflict-free unswizzled.
__global__ __launch_bounds__(256, 2) void edge_fused(
    const float* __restrict__ node_attr,
    const float* __restrict__ edge_attr,
    const float* __restrict__ edge_sh,
    const int*   __restrict__ edge_index,
    const float* __restrict__ fc1_b,
    const float* __restrict__ fc2_b,
    const short* __restrict__ fc1_wt,
    const short* __restrict__ fc2_wt,
    float* __restrict__ tp_out,
    int*   __restrict__ hist)
{
    // LDS: cbA 16384 @0 | cbB 16384 @16384 (h_s alias) | shb 4x512 @32768 | bias 6400 @34816
    __shared__ __align__(16) char lds[41216];
    char* cbA = lds;
    char* cbB = lds + 16384;
    float* bias_s = (float*)(lds + 34816);

    const int tid  = threadIdx.x;
    const int wid  = tid >> 6;          // 0..3
    const int wtid = tid & 63;
    const int l31  = wtid & 31;
    const int half = wtid >> 5;
    const int e0   = blockIdx.x * 128 + wid * 32;
    const bool active = (e0 < NEDGE);   // NEDGE % 32 == 0: whole waves

    char*  h_s = cbB + wid * 4096;      // [32 edges][128B] bf16, swizzled; dead before phase-1 DMA
    float* shb = (float*)(lds + 32768 + wid * 512);
    const int swzl = (l31 & 7) << 4;

#define STAGE1(CH, BUF, J) do { \
        const int _o = (wid * 4 + (J)) * 1024 + wtid * 16; \
        stage16((const char*)fc2_wt + (CH) * 16384 + _o, (BUF) + (wid * 4 + (J)) * 1024); \
    } while (0)
#define STAGE_FULL(CH, BUF) do { STAGE1(CH,BUF,0); STAGE1(CH,BUF,1); STAGE1(CH,BUF,2); STAGE1(CH,BUF,3); } while (0)

    STAGE_FULL(0, cbA);   // chunk 0 in flight; overlaps prologue (cbA untouched below)

    // ---- bias -> LDS (400 f32x4) ----
    *(f32x4*)(bias_s + tid * 4) = *(const f32x4*)(fc2_b + tid * 4);
    if (tid < 144)
        *(f32x4*)(bias_s + (tid + 256) * 4) = *(const f32x4*)(fc2_b + (tid + 256) * 4);

    // ---- edge meta: lanes 0..31 own one edge ----
    int dst_r = 0;
    if (active && wtid < 32) {
        dst_r = edge_index[NEDGE + e0 + wtid];
        atomicAdd(&hist[edge_index[e0 + wtid]], 1);
        *(f32x4*)(shb + wtid * 4) = *(const f32x4*)(edge_sh + (size_t)(e0 + wtid) * 4);
    }

    bf16x8 hb[4];
    f32x4 shv = {0.f, 0.f, 0.f, 0.f};
    float cb1r[16], c10r[12], c11r[4];
    int vs[2];
    vs[0] = l31 * 4;
    vs[1] = (32 + l31) * 4;

    if (active) {
        const int dstm = __shfl(dst_r, l31, 64);
        const float* nap = node_attr + (size_t)dstm * 56;
        shv = *(const f32x4*)(shb + l31 * 4);   // same-wave LDS RAW, in-order

        const f32x4 t0 = *(const f32x4*)(nap + half * 16);
        const f32x4 t1 = *(const f32x4*)(nap + half * 16 + 4);
        const f32x4 t2 = *(const f32x4*)(nap + half * 16 + 8);
        const f32x4 t3 = *(const f32x4*)(nap + half * 16 + 12);
        #pragma unroll
        for (int j = 0; j < 4; j++) {
            cb1r[j]      = INV40f * t0[j];
            cb1r[4 + j]  = INV40f * t1[j];
            cb1r[8 + j]  = INV40f * t2[j];
            cb1r[12 + j] = INV40f * t3[j];
        }
        const f32x4 y0 = *(const f32x4*)(nap + 32 + half * 12);
        const f32x4 y1 = *(const f32x4*)(nap + 32 + half * 12 + 4);
        const f32x4 y2 = *(const f32x4*)(nap + 32 + half * 12 + 8);
        float xx[12];
        #pragma unroll
        for (int j = 0; j < 4; j++) { xx[j] = y0[j]; xx[4 + j] = y1[j]; xx[8 + j] = y2[j]; }
        const float i40s0 = INV40f * shv[0];
        #pragma unroll
        for (int k = 0; k < 12; k++) c10r[k] = i40s0 * xx[k];
        #pragma unroll
        for (int e = 0; e < 4; e++)
            c11r[e] = INV120f * (xx[e*3]*shv[1] + xx[e*3+1]*shv[2] + xx[e*3+2]*shv[3]);

        // ---- fc1: h = relu(ea @ fc1_w + b) with 32x32x16 MFMA ----
        const float* pe = edge_attr + (size_t)(e0 + l31) * 64 + half * 8;
        bf16x8 eb[4];
        #pragma unroll
        for (int s = 0; s < 4; s++) {
            const f32x4 a = *(const f32x4*)(pe + s * 16);
            const f32x4 b = *(const f32x4*)(pe + s * 16 + 4);
            #pragma unroll
            for (int i = 0; i < 4; i++) { eb[s][i] = f2bf(a[i]); eb[s][4 + i] = f2bf(b[i]); }
        }
        #pragma unroll
        for (int g = 0; g < 2; g++) {
            f32x16 c;
            #pragma unroll
            for (int q = 0; q < 4; q++) {
                const f32x4 bq = *(const f32x4*)(fc1_b + g*32 + q*8 + half*4);
                c[q*4+0] = bq[0]; c[q*4+1] = bq[1]; c[q*4+2] = bq[2]; c[q*4+3] = bq[3];
            }
            #pragma unroll
            for (int s = 0; s < 4; s++) {
                const bf16x8 af = *(const bf16x8*)(fc1_wt + (g*32 + l31)*64 + s*16 + half*8);
                c = MFMA32(af, eb[s], c);
            }
            #pragma unroll
            for (int q = 0; q < 4; q++) {
                short4v p;
                #pragma unroll
                for (int j = 0; j < 4; j++) p[j] = f2bf(fmaxf(c[q*4+j], 0.0f));
                *(short4v*)(h_s + (l31*128 + ((g*64 + q*16 + half*8) ^ swzl))) = p;
            }
        }
        // read back B-frags: h[edge=l31][k = s*16 + half*8 + 0..7]
        #pragma unroll
        for (int s = 0; s < 4; s++)
            hb[s] = *(const bf16x8*)(h_s + (l31*128 + ((s*32 + half*16) ^ swzl)));
    }

    // ---- fc2 + TP consume ----
    float acc0[16] = {};
    float ab1[4] = {0,0,0,0};
    float b2[12] = {};

    // fragment-major LDS: weight frag (group go, col l31, slot t=s*2+half) at go*4096 + t*512 + l31*16
    auto mload = [&](const char* cb, int go, int G) -> f32x16 {
        f32x16 c;
        #pragma unroll
        for (int q = 0; q < 4; q++) {
            const f32x4 bq = *(const f32x4*)(bias_s + G*32 + q*8 + half*4);
            c[q*4+0] = bq[0]; c[q*4+1] = bq[1]; c[q*4+2] = bq[2]; c[q*4+3] = bq[3];
        }
        #pragma unroll
        for (int s = 0; s < 4; s++) {
            const bf16x8 a = *(const bf16x8*)(cb + go*4096 + (s*2 + half)*512 + l31*16);
            c = MFMA32(a, hb[s], c);
        }
        return c;
    };

    auto cons_w00 = [&](const char* cb, int ch) {
        #pragma unroll
        for (int go = 0; go < 4; go++) {
            const int G = ch * 4 + go;                  // u = G
            const f32x16 c = mload(cb, go, G);
            const float cv = shv[0] * bperm(vs[G >> 4], cb1r[G & 15]);
            #pragma unroll
            for (int r = 0; r < 16; r++) acc0[r] += cv * c[r];
        }
    };
    auto cons_w01 = [&](const char* cb, int Gl0) {
        #pragma unroll
        for (int go = 0; go < 4; go++) {
            const int Gl = Gl0 + go;                    // 0..7
            const f32x16 c = mload(cb, go, 32 + Gl);
            #pragma unroll
            for (int q = 0; q < 4; q++) {
                const int u = Gl * 4 + q;               // 0..31
                const float cvq = bperm(vs[u >> 4], cb1r[u & 15]);
                #pragma unroll
                for (int j = 0; j < 4; j++) ab1[j] += cvq * c[q*4+j];
            }
        }
    };
    auto cons_w10 = [&](const char* cb) {
        #pragma unroll
        for (int go = 0; go < 2; go++) {
            const f32x16 c = mload(cb, go, 40 + go);
            #pragma unroll
            for (int q = 0; q < 4; q++) {
                const int u = go * 4 + q;               // 0..7
                #pragma unroll
                for (int i = 0; i < 3; i++) {
                    const float cv = bperm(vs[u >> 2], c10r[(u & 3) * 3 + i]);
                    #pragma unroll
                    for (int j = 0; j < 4; j++) b2[j*3+i] += cv * c[q*4+j];
                }
            }
        }
    };
    auto cons_w11_2 = [&](const char* cb, int goBase, int Gl0) {
        #pragma unroll
        for (int go = 0; go < 2; go++) {
            const int Gl = Gl0 + go;                    // u = Gl (0..7)
            const f32x16 c = mload(cb, goBase + go, 42 + Gl);
            const float cv = bperm(vs[Gl >> 2], c11r[Gl & 3]);
            #pragma unroll
            for (int r = 0; r < 16; r++) acc0[r] += cv * c[r];
        }
    };
    auto cons_w11_4 = [&](const char* cb, int Gl0) {
        #pragma unroll
        for (int go = 0; go < 4; go++) {
            const int Gl = Gl0 + go;
            const f32x16 c = mload(cb, go, 42 + Gl);
            const float cv = bperm(vs[Gl >> 2], c11r[Gl & 3]);
            #pragma unroll
            for (int r = 0; r < 16; r++) acc0[r] += cv * c[r];
        }
    };

    // ---- 13-phase chunk pipeline (1 barrier/phase) ----
    __syncthreads();                                   // chunk 0 + bias ready; h reads done
    STAGE_FULL(1,  cbB); if (active) cons_w00(cbA, 0); __syncthreads();
    STAGE_FULL(2,  cbA); if (active) cons_w00(cbB, 1); __syncthreads();
    STAGE_FULL(3,  cbB); if (active) cons_w00(cbA, 2); __syncthreads();
    STAGE_FULL(4,  cbA); if (active) cons_w00(cbB, 3); __syncthreads();
    STAGE_FULL(5,  cbB); if (active) cons_w00(cbA, 4); __syncthreads();
    STAGE_FULL(6,  cbA); if (active) cons_w00(cbB, 5); __syncthreads();
    STAGE_FULL(7,  cbB); if (active) cons_w00(cbA, 6); __syncthreads();
    STAGE_FULL(8,  cbA); if (active) cons_w00(cbB, 7); __syncthreads();
    STAGE_FULL(9,  cbB); if (active) cons_w01(cbA, 0); __syncthreads();
    STAGE_FULL(10, cbA); if (active) cons_w01(cbB, 4); __syncthreads();
    STAGE_FULL(11, cbB); if (active) { cons_w10(cbA); cons_w11_2(cbA, 2, 0); } __syncthreads();
    STAGE_FULL(12, cbA); if (active) cons_w11_4(cbB, 2); __syncthreads();
                         if (active) cons_w11_2(cbA, 0, 6);

    if (!active) return;

    // ---- emit: each lane owns full (edge=l31, w-subset) results; no reductions ----
    float* orow = tp_out + (size_t)(e0 + l31) * 56;
    #pragma unroll
    for (int q = 0; q < 4; q++)
        *(f32x4*)(orow + q*8 + half*4) = f32x4{acc0[q*4], acc0[q*4+1], acc0[q*4+2], acc0[q*4+3]};
    float ov[12];
    #pragma unroll
    for (int j = 0; j < 4; j++) {
        ov[j*3 + 0] = shv[1] * ab1[j] + b2[j*3 + 0];
        ov[j*3 + 1] = shv[2] * ab1[j] + b2[j*3 + 1];
        ov[j*3 + 2] = shv[3] * ab1[j] + b2[j*3 + 2];
    }
    float* p1 = orow + 32 + half * 12;
    *(f32x4*)(p1)     = f32x4{ov[0], ov[1], ov[2],  ov[3]};
    *(f32x4*)(p1 + 4) = f32x4{ov[4], ov[5], ov[6],  ov[7]};
    *(f32x4*)(p1 + 8) = f32x4{ov[8], ov[9], ov[10], ov[11]};
#undef STAGE1
#undef STAGE_FULL
}

// exclusive prefix scan of hist[10000] -> offsets[10001], cursor (1024 threads, 10/thread)
__global__ __launch_bounds__(1024) void scan_hist(const int* __restrict__ hist,
                                                  int* __restrict__ offsets,
                                                  int* __restrict__ cursor) {
    __shared__ int part[1024];
    const int t = threadIdx.x;
    const int n0 = t * 10;
    int lh[10];
    int s = 0;
    if (n0 < NNODE) {
        #pragma unroll
        for (int j = 0; j < 10; j++) { lh[j] = hist[n0 + j]; s += lh[j]; }
    }
    part[t] = s;
    __syncthreads();
    for (int d = 1; d < 1024; d <<= 1) {
        const int v = (t >= d) ? part[t - d] : 0;
        __syncthreads();
        part[t] += v;
        __syncthreads();
    }
    if (n0 < NNODE) {
        int run = part[t] - s;
        #pragma unroll
        for (int j = 0; j < 10; j++) {
            offsets[n0 + j] = run; cursor[n0 + j] = run; run += lh[j];
        }
    }
    if (t == 0) offsets[NNODE] = NEDGE;
}

__global__ __launch_bounds__(256) void fill_perm(const int* __restrict__ edge_index,
                                                 int* __restrict__ cursor,
                                                 int* __restrict__ perm) {
    const int e = blockIdx.x * 256 + threadIdx.x;
    if (e < NEDGE) {
        const int s = edge_index[e];
        const int p = atomicAdd(&cursor[s], 1);
        perm[p] = e;
    }
}

// gather-based segment mean + residual + BN partial stats
__global__ __launch_bounds__(256) void node_agg(
    const float* __restrict__ tp_out, const int* __restrict__ offsets,
    const int* __restrict__ perm,
    const float* __restrict__ node_attr, float* __restrict__ out,
    float* __restrict__ stats)
{
    __shared__ float part[72];
    const int tid = threadIdx.x;
    if (tid < 72) part[tid] = 0.0f;
    __syncthreads();
    const int n = blockIdx.x * 16 + (tid >> 4);
    const int q = tid & 15;
    if (n < NNODE && q < 14) {
        const int st = offsets[n], en = offsets[n + 1];
        f32x4 acc = {0.f, 0.f, 0.f, 0.f};
        for (int r = st; r < en; r++)
            acc += *(const f32x4*)(tp_out + (size_t)perm[r] * 56 + q * 4);
        const float inv = 1.0f / fmaxf((float)(en - st), 1.0f);
        const int c0 = q * 4;
        const f32x4 res = *(const f32x4*)(node_attr + (size_t)n * 56 + c0);
        f32x4 val;
        #pragma unroll
        for (int j = 0; j < 4; j++) {
            val[j] = acc[j] * inv + res[j];
            const int c = c0 + j;
            if (c < 32) {
                atomicAdd(&part[c], val[j]);
                atomicAdd(&part[32 + c], val[j] * val[j]);
            } else {
                atomicAdd(&part[64 + (c - 32) / 3], val[j] * val[j]);
            }
        }
        *(f32x4*)(out + (size_t)n * 56 + c0) = val;
    }
    __syncthreads();
    if (tid < 72) unsafeAtomicAdd(&stats[tid], part[tid]);
}

__global__ __launch_bounds__(256) void node_norm(
    float* __restrict__ out, const float* __restrict__ stats,
    const float* __restrict__ g0, const float* __restrict__ b0,
    const float* __restrict__ g1)
{
    const int id = blockIdx.x * 256 + threadIdx.x;
    if (id >= NNODE * 56) return;
    const int c = id % 56;
    float val = out[id];
    if (c < 32) {
        const float m   = stats[c]      * (1.0f / NNODE);
        const float ex2 = stats[32 + c] * (1.0f / NNODE);
        const float var = ex2 - m * m;
        val = (val - m) * rsqrtf(var + 1e-5f) * g0[c] + b0[c];
    } else {
        const int v = (c - 32) / 3;
        const float vn = stats[64 + v] * (1.0f / (3.0f * NNODE));
        val = val * rsqrtf(vn + 1e-5f) * g1[v];
    }
    out[id] = val;
}

extern "C" void kernel_launch(void* const* d_in, const int* in_sizes, int n_in,
                              void* d_out, int out_size, void* d_ws, size_t ws_size,
                              hipStream_t stream) {
    const float* node_attr = (const float*)d_in[0];
    const float* edge_attr = (const float*)d_in[1];
    const float* edge_sh   = (const float*)d_in[2];
    const int*   edge_index= (const int*)  d_in[3];
    const float* fc1_w     = (const float*)d_in[4];
    const float* fc1_b     = (const float*)d_in[5];
    const float* fc2_w     = (const float*)d_in[6];
    const float* fc2_b     = (const float*)d_in[7];
    const float* g0        = (const float*)d_in[8];
    const float* b0        = (const float*)d_in[9];
    const float* g1        = (const float*)d_in[10];
    float* out = (float*)d_out;

    char* ws = (char*)d_ws;
    float* stats   = (float*)(ws + 0);
    int*   hist    = (int*)  (ws + 288);
    int*   offsets = (int*)  (ws + 40288);
    int*   cursor  = (int*)  (ws + 80320);
    int*   perm    = (int*)  (ws + 120320);
    short* fc1_wt  = (short*)(ws + 520320);
    short* fc2_wt  = (short*)(ws + 528512);
    float* tp_out  = (float*)(ws + 733312);

    prep<<<67, 256, 0, stream>>>(fc1_w, fc2_w, fc1_wt, fc2_wt, stats, hist);
    edge_fused<<<782, 256, 0, stream>>>(node_attr, edge_attr, edge_sh, edge_index,
                                        fc1_b, fc2_b, fc1_wt, fc2_wt, tp_out, hist);
    scan_hist<<<1, 1024, 0, stream>>>(hist, offsets, cursor);
    fill_perm<<<391, 256, 0, stream>>>(edge_index, cursor, perm);
    node_agg<<<625, 256, 0, stream>>>(tp_out, offsets, perm, node_attr, out, stats);
    node_norm<<<2188, 256, 0, stream>>>(out, stats, g0, b0, g1);
}